// Round 13
// baseline (91.322 us; speedup 1.0000x reference)
//
#include <hip/hip_runtime.h>
#include <hip/hip_bf16.h>

#define BB 4
#define TT 4096
#define DM 1024
#define HH 64
#define RTOT (BB * TT)   // 16384
#define SLOTS_PER_B 272  // sum_{qt=0..31} ((qt>>1)+1)
#define CHUNK 256

typedef __attribute__((ext_vector_type(4))) float f32x4;
typedef __attribute__((ext_vector_type(16))) float f32x16;
typedef __attribute__((ext_vector_type(8))) short s16x8;

#define EXP2(x) __builtin_amdgcn_exp2f(x)

__device__ __forceinline__ ushort f2bf_bits(float f) {
    union { float f; unsigned u; } x;
    x.f = f;
    unsigned r = x.u + 0x7FFFu + ((x.u >> 16) & 1u);  // RNE to bf16
    return (ushort)(r >> 16);
}

__device__ __forceinline__ float bf2f(ushort u) {
    union { unsigned i; float f; } x;
    x.i = ((unsigned)u) << 16;
    return x.f;
}

__device__ __forceinline__ unsigned pack2bf(float lo, float hi) {
    return (unsigned)f2bf_bits(lo) | ((unsigned)f2bf_bits(hi) << 16);
}

// async global->LDS, 16B per lane; LDS dest = wave-uniform base + lane*16
__device__ __forceinline__ void gld_lds16(const void* g, void* l) {
    __builtin_amdgcn_global_load_lds(
        (const __attribute__((address_space(1))) void*)g,
        (__attribute__((address_space(3))) void*)l, 16, 0, 0);
}

// ---- W relayout: wt2[m][kk][f][lane][8] -> one contiguous 1KB per (kk,f).
// wt2 elem = W^T[(l&15)+16f][kk*32+(l>>4)*8+j]. Wq gets log2e/8 folded in.
__global__ __launch_bounds__(256) void k_wtrans(const float* __restrict__ wq,
                                                const float* __restrict__ wk,
                                                const float* __restrict__ wv,
                                                ushort* __restrict__ wt) {
    int idx = blockIdx.x * 256 + threadIdx.x;   // 0 .. 3*65536-1
    int m = idx >> 16, e = idx & 65535;
    int kk = e >> 11, r = e & 2047;
    int f = r >> 9, s = r & 511;
    int l = s >> 3, j = s & 7;
    int col = (l & 15) + 16 * f;
    int kd  = kk * 32 + (l >> 4) * 8 + j;
    const float* W = (m == 0) ? wq : (m == 1) ? wk : wv;
    float v = W[kd * HH + col];
    if (m == 0) v *= 0.1803368801111204f;  // log2(e)/8 folded into Q projection
    wt[idx] = f2bf_bits(v);
}

// ---- projections v4 (unchanged from R12): in-block K-split, 8 waves ----
__global__ __launch_bounds__(512, 6) void k_proj(const float* __restrict__ q,
                                                 const float* __restrict__ k,
                                                 const float* __restrict__ v,
                                                 const ushort* __restrict__ wt,
                                                 ushort* __restrict__ qh,
                                                 ushort* __restrict__ kh,
                                                 ushort* __restrict__ vt) {
    int bid = blockIdx.x;        // 0..767
    int mat = bid >> 8;
    int rt  = bid & 255;
    const float* src = (mat == 0) ? q : (mat == 1) ? k : v;
    const ushort* w2 = wt + mat * 65536;

    __shared__ __align__(16) char ldsx[49152];   // 8 waves x 3 x 2KB A-ring

    int t = threadIdx.x;
    int w = t >> 6, l = t & 63, lr = l & 15, lg = l >> 4;
    int ws = w & 3, kh2 = w >> 2;
    int rbase = rt * 64;
    int ph = bid & 15;   // K-phase stagger within the half

    int ca = (l & 7) ^ ((l >> 3) & 7);
    const float* ag0 = src + (size_t)(rbase + ws * 16 + (l >> 3)) * DM + kh2 * 512 + ca * 4;
    const float* ag1 = ag0 + 8 * DM;
    char* abase = ldsx + w * 6144;

    int ax0 = (lr * 128 + lg * 32) ^ ((lr & 7) << 4);
    int wko = kh2 * 16;

    f32x4 acc[4] = {};
    s16x8 wA[4], wB[4];

#define KK(jj) ((((jj) + ph) & 15))
#define LOADW(dst, jj) do { int kk_ = wko + KK(jj);                               \
    dst[0] = *reinterpret_cast<const s16x8*>(w2 + (kk_ * 4 + 0) * 512 + l * 8);   \
    dst[1] = *reinterpret_cast<const s16x8*>(w2 + (kk_ * 4 + 1) * 512 + l * 8);   \
    dst[2] = *reinterpret_cast<const s16x8*>(w2 + (kk_ * 4 + 2) * 512 + l * 8);   \
    dst[3] = *reinterpret_cast<const s16x8*>(w2 + (kk_ * 4 + 3) * 512 + l * 8); } while (0)
#define STAGEA(jj) do { int ko_ = KK(jj) * 32; int bo_ = ((jj) % 3) * 2048;       \
    gld_lds16(ag0 + ko_, abase + bo_);                                            \
    gld_lds16(ag1 + ko_, abase + bo_ + 1024); } while (0)

    LOADW(wA, 0); STAGEA(0);
    LOADW(wB, 1); STAGEA(1);

#define BODY(jj, WCUR, VM) do {                                                   \
    asm volatile("s_waitcnt vmcnt(" #VM ")" ::: "memory");                        \
    __builtin_amdgcn_sched_barrier(0);                                            \
    {                                                                             \
        const char* ab = abase + ((jj) % 3) * 2048;                               \
        f32x4 av0 = *reinterpret_cast<const f32x4*>(ab + ax0);                    \
        f32x4 av1 = *reinterpret_cast<const f32x4*>(ab + (ax0 ^ 16));             \
        s16x8 af;                                                                 \
        af[0] = f2bf_bits(av0[0]); af[1] = f2bf_bits(av0[1]);                     \
        af[2] = f2bf_bits(av0[2]); af[3] = f2bf_bits(av0[3]);                     \
        af[4] = f2bf_bits(av1[0]); af[5] = f2bf_bits(av1[1]);                     \
        af[6] = f2bf_bits(av1[2]); af[7] = f2bf_bits(av1[3]);                     \
        acc[0] = __builtin_amdgcn_mfma_f32_16x16x32_bf16(af, WCUR[0], acc[0], 0, 0, 0); \
        acc[1] = __builtin_amdgcn_mfma_f32_16x16x32_bf16(af, WCUR[1], acc[1], 0, 0, 0); \
        acc[2] = __builtin_amdgcn_mfma_f32_16x16x32_bf16(af, WCUR[2], acc[2], 0, 0, 0); \
        acc[3] = __builtin_amdgcn_mfma_f32_16x16x32_bf16(af, WCUR[3], acc[3], 0, 0, 0); \
    }                                                                             \
    __builtin_amdgcn_sched_barrier(0);                                            \
    if ((jj) + 2 < 16) { LOADW(WCUR, (jj) + 2); STAGEA((jj) + 2); }               \
} while (0)

    BODY(0,  wA, 6);  BODY(1,  wB, 6);  BODY(2,  wA, 6);  BODY(3,  wB, 6);
    BODY(4,  wA, 6);  BODY(5,  wB, 6);  BODY(6,  wA, 6);  BODY(7,  wB, 6);
    BODY(8,  wA, 6);  BODY(9,  wB, 6);  BODY(10, wA, 6);  BODY(11, wB, 6);
    BODY(12, wA, 6);  BODY(13, wB, 6);  BODY(14, wA, 6);  BODY(15, wB, 0);
#undef BODY
#undef STAGEA
#undef LOADW
#undef KK

    __syncthreads();
    float* xb = (float*)ldsx;  // xbuf[ws][16][65] fp32
    if (kh2 == 1) {
#pragma unroll
        for (int f = 0; f < 4; ++f)
#pragma unroll
            for (int r = 0; r < 4; ++r)
                xb[ws * 1040 + (lg * 4 + r) * 65 + lr + 16 * f] = acc[f][r];
    }
    __syncthreads();
    if (kh2 == 0) {
#pragma unroll
        for (int f = 0; f < 4; ++f)
#pragma unroll
            for (int r = 0; r < 4; ++r) {
                float sum = acc[f][r] + xb[ws * 1040 + (lg * 4 + r) * 65 + lr + 16 * f];
                int row = rbase + ws * 16 + lg * 4 + r;
                int col = lr + 16 * f;
                ushort bv = f2bf_bits(sum);
                if (mat == 0)      qh[row * HH + col] = bv;
                else if (mat == 1) kh[row * HH + col] = bv;
                else               vt[(size_t)col * RTOT + row] = bv;
            }
    }
}

// ---- attention: swapped-QK/swapped-PV flash, LDS-staged K/V, split-KV ----
// CHUNK=256: 1088 live blocks (4.25/CU) for tail amortization; pO in bf16.
__global__ __launch_bounds__(256, 2) void k_attn(const ushort* __restrict__ qh,
                                                 const ushort* __restrict__ kh,
                                                 const ushort* __restrict__ vt,
                                                 float* __restrict__ pm,
                                                 float* __restrict__ pl,
                                                 ushort* __restrict__ pO) {
    int c = blockIdx.x, qt = blockIdx.y, b = blockIdx.z;
    int m_ = qt >> 1, e_ = qt & 1;
    int nch = m_ + 1;
    if (c >= nch) return;
    int slot = b * SLOTS_PER_B + m_ * (m_ + 1) + e_ * (m_ + 1) + c;

    __shared__ __align__(16) ushort kbuf[2][2048];  // [buf][32 kv x 64 d], XOR-swizzled
    __shared__ __align__(16) ushort vbuf[2][2048];  // [buf][64 h x 32 kv], XOR-swizzled

    int t = threadIdx.x, w = t >> 6, l = t & 63, lq = l & 31, hf = l >> 5;
    int W0 = qt * 128 + w * 32;       // wave q base (batch-local)
    size_t bT = (size_t)b * TT;
    int kv0 = c * CHUNK;
    int kvend = min(kv0 + CHUNK, (qt + 1) * 128);
    int nsteps = (kvend - kv0) >> 5;
    bool diag = (c == nch - 1);

    // Q^T B-fragments (col=l&31=q, k=(l>>5)*8+j), 4 k-steps of 16
    s16x8 qf[4];
#pragma unroll
    for (int s = 0; s < 4; ++s)
        qf[s] = *reinterpret_cast<const s16x8*>(qh + (bT + W0 + lq) * HH + s * 16 + hf * 8);

    // staging addresses (reg-stage: global -> regs -> swizzled ds_write)
    int krow = t >> 3, kch = t & 7;
    int vrow = t >> 2, vch = t & 3;
    const ushort* kgp = kh + (bT + kv0 + krow) * HH + kch * 8;
    const ushort* vgp = vt + (size_t)vrow * RTOT + bT + kv0 + vch * 8;
    int kwo = (krow * 128 + kch * 16) ^ ((krow & 7) << 4);
    int vwo = (vrow * 64 + vch * 16) ^ ((vrow & 7) << 4);

    uint4 ks = *reinterpret_cast<const uint4*>(kgp);
    uint4 vs = *reinterpret_cast<const uint4*>(vgp);
    *reinterpret_cast<uint4*>(reinterpret_cast<char*>(&kbuf[0][0]) + kwo) = ks;
    *reinterpret_cast<uint4*>(reinterpret_cast<char*>(&vbuf[0][0]) + vwo) = vs;

    float m = -1e30f, ssum = 0.f;
    f32x16 oacc0 = {}, oacc1 = {};

    for (int j = 0; j < nsteps; ++j) {
        int cur = j & 1;
        if (j + 1 < nsteps) {  // issue next tile's global loads early (T14)
            ks = *reinterpret_cast<const uint4*>(kgp + (j + 1) * 32 * HH);
            vs = *reinterpret_cast<const uint4*>(vgp + (j + 1) * 32);
        }
        __syncthreads();  // buf[cur] writes visible
        int kvb = kv0 + j * 32;
        bool skip = diag && (kvb > W0 + 31);
        if (!skip) {
            const char* kb_ = reinterpret_cast<const char*>(&kbuf[cur][0]);
            const char* vb_ = reinterpret_cast<const char*>(&vbuf[cur][0]);
            // QK^T swapped: C1[kv][q], lane: q=l&31, kv=(reg&3)+8(reg>>2)+4hf
            f32x16 sacc = {};
#pragma unroll
            for (int s = 0; s < 4; ++s) {
                int ko = (lq * 128 + s * 32 + hf * 16) ^ ((lq & 7) << 4);
                s16x8 kf = *reinterpret_cast<const s16x8*>(kb_ + ko);
                sacc = __builtin_amdgcn_mfma_f32_32x32x16_bf16(kf, qf[s], sacc, 0, 0, 0);
            }
            if (diag && (kvb + 31 > W0)) {  // partial diagonal step
                int qcol = W0 + lq;
#pragma unroll
                for (int g = 0; g < 16; ++g) {
                    int kvr = kvb + (g & 3) + 8 * (g >> 2) + 4 * hf;
                    if (kvr > qcol) sacc[g] = -1e30f;
                }
            }
            // online softmax, lane-local; cross-half combine via shfl_xor(32)
            float t0 = fmaxf(fmaxf(fmaxf(sacc[0], sacc[1]), fmaxf(sacc[2], sacc[3])),
                             fmaxf(fmaxf(sacc[4], sacc[5]), fmaxf(sacc[6], sacc[7])));
            float t1 = fmaxf(fmaxf(fmaxf(sacc[8], sacc[9]), fmaxf(sacc[10], sacc[11])),
                             fmaxf(fmaxf(sacc[12], sacc[13]), fmaxf(sacc[14], sacc[15])));
            float tmx = fmaxf(t0, t1);
            tmx = fmaxf(tmx, __shfl_xor(tmx, 32));
            float mnew = fmaxf(m, tmx);
            float corr = EXP2(m - mnew);
            float p[16];
#pragma unroll
            for (int g = 0; g < 16; ++g) p[g] = EXP2(sacc[g] - mnew);
            float ts = ((p[0] + p[1]) + (p[2] + p[3])) + ((p[4] + p[5]) + (p[6] + p[7]))
                     + ((p[8] + p[9]) + (p[10] + p[11])) + ((p[12] + p[13]) + (p[14] + p[15]));
            ts += __shfl_xor(ts, 32);
            ssum = ssum * corr + ts;
            m = mnew;
#pragma unroll
            for (int g = 0; g < 16; ++g) { oacc0[g] *= corr; oacc1[g] *= corr; }
            // pack P -> PV B-fragments: pure-C bf16 pack + shfl_xor(32) redistribution
            unsigned d0 = pack2bf(p[0], p[1]),   d1 = pack2bf(p[2], p[3]);
            unsigned d2 = pack2bf(p[4], p[5]),   d3 = pack2bf(p[6], p[7]);
            unsigned d4 = pack2bf(p[8], p[9]),   d5 = pack2bf(p[10], p[11]);
            unsigned d6 = pack2bf(p[12], p[13]), d7 = pack2bf(p[14], p[15]);
            unsigned s0 = __shfl_xor(d0, 32), s1 = __shfl_xor(d1, 32);
            unsigned s2 = __shfl_xor(d2, 32), s3 = __shfl_xor(d3, 32);
            unsigned s4 = __shfl_xor(d4, 32), s5 = __shfl_xor(d5, 32);
            unsigned s6 = __shfl_xor(d6, 32), s7 = __shfl_xor(d7, 32);
            union { unsigned u[4]; s16x8 v; } pf0, pf1;
            pf0.u[0] = hf ? s2 : d0;  pf0.u[1] = hf ? s3 : d1;
            pf0.u[2] = hf ? d2 : s0;  pf0.u[3] = hf ? d3 : s1;
            pf1.u[0] = hf ? s6 : d4;  pf1.u[1] = hf ? s7 : d5;
            pf1.u[2] = hf ? d6 : s4;  pf1.u[3] = hf ? d7 : s5;
            // PV swapped: C2[h][q] += Vt[h][kv] * P[kv][q]
#pragma unroll
            for (int ts2 = 0; ts2 < 2; ++ts2) {
                int vo0 = ((0 * 32 + lq) * 64 + ts2 * 32 + hf * 16) ^ ((lq & 7) << 4);
                int vo1 = ((1 * 32 + lq) * 64 + ts2 * 32 + hf * 16) ^ ((lq & 7) << 4);
                s16x8 vf0 = *reinterpret_cast<const s16x8*>(vb_ + vo0);
                s16x8 vf1 = *reinterpret_cast<const s16x8*>(vb_ + vo1);
                s16x8 pf = ts2 ? pf1.v : pf0.v;
                oacc0 = __builtin_amdgcn_mfma_f32_32x32x16_bf16(vf0, pf, oacc0, 0, 0, 0);
                oacc1 = __builtin_amdgcn_mfma_f32_32x32x16_bf16(vf1, pf, oacc1, 0, 0, 0);
            }
        }
        __syncthreads();  // everyone done reading buf[cur]
        if (j + 1 < nsteps) {
            *reinterpret_cast<uint4*>(reinterpret_cast<char*>(&kbuf[cur ^ 1][0]) + kwo) = ks;
            *reinterpret_cast<uint4*>(reinterpret_cast<char*>(&vbuf[cur ^ 1][0]) + vwo) = vs;
        }
    }

    if (l < 32) {
        pm[(size_t)slot * 128 + w * 32 + l] = m;
        pl[(size_t)slot * 128 + w * 32 + l] = ssum;
    }
    ushort* po = pO + (size_t)slot * 8192;  // [64 h][128 q] bf16
#pragma unroll
    for (int g = 0; g < 16; ++g) {
        int hrow = (g & 3) + 8 * (g >> 2) + 4 * hf;
        po[hrow * 128 + w * 32 + lq] = f2bf_bits(oacc0[g]);
        po[(32 + hrow) * 128 + w * 32 + lq] = f2bf_bits(oacc1[g]);
    }
}

// ---- merge partials (bf16 pO, up to 16 chunks): one block per (b, qtile) ----
__global__ __launch_bounds__(256) void k_merge(const float* __restrict__ pm,
                                               const float* __restrict__ pl,
                                               const ushort* __restrict__ pO,
                                               float* __restrict__ out) {
    int qt = blockIdx.x & 31, b = blockIdx.x >> 5;
    int m_ = qt >> 1, e_ = qt & 1, nch = m_ + 1;
    int slot0 = b * SLOTS_PER_B + m_ * (m_ + 1) + e_ * (m_ + 1);

    __shared__ float wgt[16][128];
    __shared__ float invl[128];
    __shared__ float tr[64][130];

    int t = threadIdx.x;
    if (t < 128) {
        float M = -3e38f;
        for (int cc = 0; cc < nch; ++cc)
            M = fmaxf(M, pm[(size_t)(slot0 + cc) * 128 + t]);
        float L = 0.f;
        for (int cc = 0; cc < nch; ++cc) {
            float g = EXP2(pm[(size_t)(slot0 + cc) * 128 + t] - M);
            wgt[cc][t] = g;
            L += pl[(size_t)(slot0 + cc) * 128 + t] * g;
        }
        invl[t] = 1.0f / L;
    }
    __syncthreads();

    float acc[32] = {};
    for (int cc = 0; cc < nch; ++cc) {
        const ushort* pp = pO + (size_t)(slot0 + cc) * 8192;
#pragma unroll
        for (int it = 0; it < 8; ++it) {
            int e = it * 1024 + t * 4;       // elem = h*128 + q
            int qc = e & 127;
            ushort4 v4 = *reinterpret_cast<const ushort4*>(pp + e);
            acc[it * 4 + 0] += bf2f(v4.x) * wgt[cc][qc + 0];
            acc[it * 4 + 1] += bf2f(v4.y) * wgt[cc][qc + 1];
            acc[it * 4 + 2] += bf2f(v4.z) * wgt[cc][qc + 2];
            acc[it * 4 + 3] += bf2f(v4.w) * wgt[cc][qc + 3];
        }
    }
#pragma unroll
    for (int it = 0; it < 8; ++it) {
        int e = it * 1024 + t * 4;
        int h = e >> 7, qc = e & 127;
        tr[h][qc + 0] = acc[it * 4 + 0] * invl[qc + 0];
        tr[h][qc + 1] = acc[it * 4 + 1] * invl[qc + 1];
        tr[h][qc + 2] = acc[it * 4 + 2] * invl[qc + 2];
        tr[h][qc + 3] = acc[it * 4 + 3] * invl[qc + 3];
    }
    __syncthreads();

    int q = t >> 1, half = t & 1;
    size_t obase = ((size_t)b * TT + qt * 128 + q) * 64 + half * 32;
#pragma unroll
    for (int jj = 0; jj < 8; ++jj) {
        float4 o;
        o.x = tr[half * 32 + jj * 4 + 0][q];
        o.y = tr[half * 32 + jj * 4 + 1][q];
        o.z = tr[half * 32 + jj * 4 + 2][q];
        o.w = tr[half * 32 + jj * 4 + 3][q];
        *reinterpret_cast<float4*>(out + obase + jj * 4) = o;
    }
}

extern "C" void kernel_launch(void* const* d_in, const int* in_sizes, int n_in,
                              void* d_out, int out_size, void* d_ws, size_t ws_size,
                              hipStream_t stream) {
    const float* q  = (const float*)d_in[0];
    const float* k  = (const float*)d_in[1];
    const float* v  = (const float*)d_in[2];
    const float* wq = (const float*)d_in[3];
    const float* wk = (const float*)d_in[4];
    const float* wv = (const float*)d_in[5];
    float* out = (float*)d_out;

    char* ws = (char*)d_ws;
    ushort* qh = (ushort*)(ws);                   // 2 MB   [16384][64] bf16
    ushort* kh = (ushort*)(ws + (2ull << 20));    // 2 MB   [16384][64] bf16
    ushort* vt = (ushort*)(ws + (4ull << 20));    // 2 MB   [64][16384] bf16
    ushort* wt = (ushort*)(ws + (6ull << 20));    // 384 KB [3][32][4][64][8] bf16
    float*  pm = (float*)(ws + (7ull << 20));     // 544 KB [1088][128]
    float*  pl = (float*)(ws + (8ull << 20));     // 544 KB
    ushort* pO = (ushort*)(ws + (9ull << 20));    // 17.8 MB [1088][64][128] bf16

    k_wtrans<<<768, 256, 0, stream>>>(wq, wk, wv, wt);
    k_proj<<<768, 512, 0, stream>>>(q, k, v, wt, qh, kh, vt);
    k_attn<<<dim3(16, 32, 4), 256, 0, stream>>>(qh, kh, vt, pm, pl, pO);
    k_merge<<<128, 256, 0, stream>>>(pm, pl, pO, out);
}

// Round 14
// 85.940 us; speedup vs baseline: 1.0626x; 1.0626x over previous
//
#include <hip/hip_runtime.h>
#include <hip/hip_bf16.h>

#define BB 4
#define TT 4096
#define DM 1024
#define HH 64
#define RTOT (BB * TT)   // 16384
#define SLOTS_PER_B 144  // sum_{qt=0..31} ((qt>>2)+1)
#define CHUNK 512

typedef __attribute__((ext_vector_type(4))) float f32x4;
typedef __attribute__((ext_vector_type(16))) float f32x16;
typedef __attribute__((ext_vector_type(8))) short s16x8;

#define EXP2(x) __builtin_amdgcn_exp2f(x)

__device__ __forceinline__ ushort f2bf_bits(float f) {
    union { float f; unsigned u; } x;
    x.f = f;
    unsigned r = x.u + 0x7FFFu + ((x.u >> 16) & 1u);  // RNE to bf16
    return (ushort)(r >> 16);
}

__device__ __forceinline__ unsigned pack2bf(float lo, float hi) {
    return (unsigned)f2bf_bits(lo) | ((unsigned)f2bf_bits(hi) << 16);
}

// async global->LDS, 16B per lane; LDS dest = wave-uniform base + lane*16
__device__ __forceinline__ void gld_lds16(const void* g, void* l) {
    __builtin_amdgcn_global_load_lds(
        (const __attribute__((address_space(1))) void*)g,
        (__attribute__((address_space(3))) void*)l, 16, 0, 0);
}

// ---- transpose + convert W: wt[m][h][d]; Wq gets log2e/8 folded in ----
__global__ __launch_bounds__(256) void k_wtrans(const float* __restrict__ wq,
                                                const float* __restrict__ wk,
                                                const float* __restrict__ wv,
                                                ushort* __restrict__ wt) {
    int idx = blockIdx.x * 256 + threadIdx.x;
    int m = idx >> 16, rem = idx & 65535;
    int h = rem >> 10, d = rem & 1023;
    const float* W = (m == 0) ? wq : (m == 1) ? wk : wv;
    float v = W[d * HH + h];
    if (m == 0) v *= 0.1803368801111204f;  // log2(e)/8 folded into Q projection
    wt[idx] = f2bf_bits(v);
}

// ---- projections via global_load_lds staging (m97 pattern) ----
// block: 64 rows x 64 cols, K=1024 in 32 steps of 32.
// LDS: A-slice fp32 [64r][32k] 8KB + W-slice bf16 [64h][32k] 4KB, both
// XOR-swizzled ((row&7)<<4) via pre-swizzled GLOBAL source (linear LDS dest).
__global__ __launch_bounds__(256) void k_proj(const float* __restrict__ q,
                                              const float* __restrict__ k,
                                              const float* __restrict__ v,
                                              const ushort* __restrict__ wt,
                                              ushort* __restrict__ qh,
                                              ushort* __restrict__ kh,
                                              ushort* __restrict__ vt) {
    int bid = blockIdx.x;
    int mat = bid >> 8;
    int rt  = bid & 255;
    const float* src = (mat == 0) ? q : (mat == 1) ? k : v;
    const ushort* w = wt + mat * (HH * DM);

    __shared__ __align__(16) float  abuf[2][2048];   // 2 x 8KB
    __shared__ __align__(16) ushort wbuf[2][2048];   // 2 x 4KB

    int t = threadIdx.x;
    int wv_ = t >> 6, l = t & 63, lr = l & 15, lg = l >> 4;
    int rbase = rt * 64;

    // --- staging sources (inverse-swizzled so LDS-linear == swizzled layout) ---
    int rowa = t >> 3;                         // + 32 for issue 1
    int ca   = (t & 7) ^ (rowa & 7);
    const float* ag0 = src + (size_t)(rbase + rowa) * DM + ca * 4;
    const float* ag1 = src + (size_t)(rbase + rowa + 32) * DM + ca * 4;
    int h_ = 2 * (t >> 3) + (((t >> 2) ^ (t >> 4)) & 1);
    int cw = ((t ^ (t >> 2) ^ (t >> 4)) & 1) + 2 * (((t >> 1) ^ (t >> 3)) & 1);
    const ushort* wg = w + h_ * DM + cw * 8;

    // --- fragment read offsets (swizzled) ---
    int arow = wv_ * 16 + lr;
    int ax0 = (arow * 128 + lg * 32) ^ ((lr & 7) << 4);
    int wx0 = ((lr +  0) * 64 + lg * 16) ^ ((lr & 7) << 4);
    int wx1 = ((lr + 16) * 64 + lg * 16) ^ ((lr & 7) << 4);
    int wx2 = ((lr + 32) * 64 + lg * 16) ^ ((lr & 7) << 4);
    int wx3 = ((lr + 48) * 64 + lg * 16) ^ ((lr & 7) << 4);

    f32x4 acc[4] = {};

#define STAGE(bf, kofs)                                                          \
    do {                                                                         \
        gld_lds16(ag0 + (kofs), (char*)&abuf[bf][0] + wv_ * 1024);               \
        gld_lds16(ag1 + (kofs), (char*)&abuf[bf][0] + 4096 + wv_ * 1024);        \
        gld_lds16(wg  + (kofs), (char*)&wbuf[bf][0] + wv_ * 1024);               \
    } while (0)

    STAGE(0, 0);
    __syncthreads();   // vmcnt(0)+lgkmcnt(0)+barrier: buf0 ready

    int cur = 0;
    for (int ks = 0; ks < 32; ++ks) {
        if (ks < 31) STAGE(cur ^ 1, (ks + 1) * 32);  // issue next-tile loads early
        const char* ab = (const char*)&abuf[cur][0];
        const char* wb = (const char*)&wbuf[cur][0];
        f32x4 av0 = *reinterpret_cast<const f32x4*>(ab + ax0);
        f32x4 av1 = *reinterpret_cast<const f32x4*>(ab + (ax0 ^ 16));
        s16x8 af;
        af[0] = f2bf_bits(av0[0]); af[1] = f2bf_bits(av0[1]);
        af[2] = f2bf_bits(av0[2]); af[3] = f2bf_bits(av0[3]);
        af[4] = f2bf_bits(av1[0]); af[5] = f2bf_bits(av1[1]);
        af[6] = f2bf_bits(av1[2]); af[7] = f2bf_bits(av1[3]);
        s16x8 b0 = *reinterpret_cast<const s16x8*>(wb + wx0);
        s16x8 b1 = *reinterpret_cast<const s16x8*>(wb + wx1);
        s16x8 b2 = *reinterpret_cast<const s16x8*>(wb + wx2);
        s16x8 b3 = *reinterpret_cast<const s16x8*>(wb + wx3);
        acc[0] = __builtin_amdgcn_mfma_f32_16x16x32_bf16(af, b0, acc[0], 0, 0, 0);
        acc[1] = __builtin_amdgcn_mfma_f32_16x16x32_bf16(af, b1, acc[1], 0, 0, 0);
        acc[2] = __builtin_amdgcn_mfma_f32_16x16x32_bf16(af, b2, acc[2], 0, 0, 0);
        acc[3] = __builtin_amdgcn_mfma_f32_16x16x32_bf16(af, b3, acc[3], 0, 0, 0);
        __syncthreads();   // drain next-tile glds + protect buf reuse
        cur ^= 1;
    }
#undef STAGE

#pragma unroll
    for (int f = 0; f < 4; ++f)
#pragma unroll
        for (int r = 0; r < 4; ++r) {
            int row = rbase + wv_ * 16 + lg * 4 + r;
            int col = lr + 16 * f;
            ushort bv = f2bf_bits(acc[f][r]);
            if (mat == 0)      qh[row * HH + col] = bv;
            else if (mat == 1) kh[row * HH + col] = bv;
            else               vt[(size_t)col * RTOT + row] = bv;
        }
}

// ---- attention: swapped-QK/swapped-PV flash, LDS-staged K/V, split-KV ----
// block = 256 thr = 4 waves; wave w owns 32 q-rows; block = 128 q-rows x <=512 kv
__global__ __launch_bounds__(256, 2) void k_attn(const ushort* __restrict__ qh,
                                                 const ushort* __restrict__ kh,
                                                 const ushort* __restrict__ vt,
                                                 float* __restrict__ pm,
                                                 float* __restrict__ pl,
                                                 float* __restrict__ pO) {
    int c = blockIdx.x, qt = blockIdx.y, b = blockIdx.z;
    int a = qt >> 2, r = qt & 3;
    int nch = a + 1;
    if (c >= nch) return;
    int slot = b * SLOTS_PER_B + 2 * a * (a + 1) + r * (a + 1) + c;

    __shared__ __align__(16) ushort kbuf[2][2048];  // [buf][32 kv x 64 d], XOR-swizzled
    __shared__ __align__(16) ushort vbuf[2][2048];  // [buf][64 h x 32 kv], XOR-swizzled

    int t = threadIdx.x, w = t >> 6, l = t & 63, lq = l & 31, hf = l >> 5;
    int W0 = qt * 128 + w * 32;       // wave q base (batch-local)
    size_t bT = (size_t)b * TT;
    int kv0 = c * CHUNK;
    int kvend = min(kv0 + CHUNK, (qt + 1) * 128);
    int nsteps = (kvend - kv0) >> 5;
    bool diag = (c == nch - 1);

    // Q^T B-fragments (col=l&31=q, k=(l>>5)*8+j), 4 k-steps of 16
    s16x8 qf[4];
#pragma unroll
    for (int s = 0; s < 4; ++s)
        qf[s] = *reinterpret_cast<const s16x8*>(qh + (bT + W0 + lq) * HH + s * 16 + hf * 8);

    // staging addresses (reg-stage: global -> regs -> swizzled ds_write)
    int krow = t >> 3, kch = t & 7;
    int vrow = t >> 2, vch = t & 3;
    const ushort* kgp = kh + (bT + kv0 + krow) * HH + kch * 8;
    const ushort* vgp = vt + (size_t)vrow * RTOT + bT + kv0 + vch * 8;
    int kwo = (krow * 128 + kch * 16) ^ ((krow & 7) << 4);
    int vwo = (vrow * 64 + vch * 16) ^ ((vrow & 7) << 4);

    uint4 ks = *reinterpret_cast<const uint4*>(kgp);
    uint4 vs = *reinterpret_cast<const uint4*>(vgp);
    *reinterpret_cast<uint4*>(reinterpret_cast<char*>(&kbuf[0][0]) + kwo) = ks;
    *reinterpret_cast<uint4*>(reinterpret_cast<char*>(&vbuf[0][0]) + vwo) = vs;

    float m = -1e30f, ssum = 0.f;
    f32x16 oacc0 = {}, oacc1 = {};

    for (int j = 0; j < nsteps; ++j) {
        int cur = j & 1;
        if (j + 1 < nsteps) {  // issue next tile's global loads early (T14)
            ks = *reinterpret_cast<const uint4*>(kgp + (j + 1) * 32 * HH);
            vs = *reinterpret_cast<const uint4*>(vgp + (j + 1) * 32);
        }
        __syncthreads();  // buf[cur] writes visible
        int kvb = kv0 + j * 32;
        bool skip = diag && (kvb > W0 + 31);
        if (!skip) {
            const char* kb_ = reinterpret_cast<const char*>(&kbuf[cur][0]);
            const char* vb_ = reinterpret_cast<const char*>(&vbuf[cur][0]);
            // QK^T swapped: C1[kv][q], lane: q=l&31, kv=(reg&3)+8(reg>>2)+4hf
            f32x16 sacc = {};
#pragma unroll
            for (int s = 0; s < 4; ++s) {
                int ko = (lq * 128 + s * 32 + hf * 16) ^ ((lq & 7) << 4);
                s16x8 kf = *reinterpret_cast<const s16x8*>(kb_ + ko);
                sacc = __builtin_amdgcn_mfma_f32_32x32x16_bf16(kf, qf[s], sacc, 0, 0, 0);
            }
            if (diag && (kvb + 31 > W0)) {  // partial diagonal step
                int qcol = W0 + lq;
#pragma unroll
                for (int g = 0; g < 16; ++g) {
                    int kvr = kvb + (g & 3) + 8 * (g >> 2) + 4 * hf;
                    if (kvr > qcol) sacc[g] = -1e30f;
                }
            }
            // online softmax, lane-local; cross-half combine via shfl_xor(32)
            float t0 = fmaxf(fmaxf(fmaxf(sacc[0], sacc[1]), fmaxf(sacc[2], sacc[3])),
                             fmaxf(fmaxf(sacc[4], sacc[5]), fmaxf(sacc[6], sacc[7])));
            float t1 = fmaxf(fmaxf(fmaxf(sacc[8], sacc[9]), fmaxf(sacc[10], sacc[11])),
                             fmaxf(fmaxf(sacc[12], sacc[13]), fmaxf(sacc[14], sacc[15])));
            float tmx = fmaxf(t0, t1);
            tmx = fmaxf(tmx, __shfl_xor(tmx, 32));
            float mnew = fmaxf(m, tmx);
            float corr = EXP2(m - mnew);
            float p[16];
#pragma unroll
            for (int g = 0; g < 16; ++g) p[g] = EXP2(sacc[g] - mnew);
            float ts = ((p[0] + p[1]) + (p[2] + p[3])) + ((p[4] + p[5]) + (p[6] + p[7]))
                     + ((p[8] + p[9]) + (p[10] + p[11])) + ((p[12] + p[13]) + (p[14] + p[15]));
            ts += __shfl_xor(ts, 32);
            ssum = ssum * corr + ts;
            m = mnew;
#pragma unroll
            for (int g = 0; g < 16; ++g) { oacc0[g] *= corr; oacc1[g] *= corr; }
            // pack P -> PV B-fragments: pure-C bf16 pack + shfl_xor(32) redistribution
            unsigned d0 = pack2bf(p[0], p[1]),   d1 = pack2bf(p[2], p[3]);
            unsigned d2 = pack2bf(p[4], p[5]),   d3 = pack2bf(p[6], p[7]);
            unsigned d4 = pack2bf(p[8], p[9]),   d5 = pack2bf(p[10], p[11]);
            unsigned d6 = pack2bf(p[12], p[13]), d7 = pack2bf(p[14], p[15]);
            unsigned s0 = __shfl_xor(d0, 32), s1 = __shfl_xor(d1, 32);
            unsigned s2 = __shfl_xor(d2, 32), s3 = __shfl_xor(d3, 32);
            unsigned s4 = __shfl_xor(d4, 32), s5 = __shfl_xor(d5, 32);
            unsigned s6 = __shfl_xor(d6, 32), s7 = __shfl_xor(d7, 32);
            union { unsigned u[4]; s16x8 v; } pf0, pf1;
            pf0.u[0] = hf ? s2 : d0;  pf0.u[1] = hf ? s3 : d1;
            pf0.u[2] = hf ? d2 : s0;  pf0.u[3] = hf ? d3 : s1;
            pf1.u[0] = hf ? s6 : d4;  pf1.u[1] = hf ? s7 : d5;
            pf1.u[2] = hf ? d6 : s4;  pf1.u[3] = hf ? d7 : s5;
            // PV swapped: C2[h][q] += Vt[h][kv] * P[kv][q]
#pragma unroll
            for (int ts2 = 0; ts2 < 2; ++ts2) {
                int vo0 = ((0 * 32 + lq) * 64 + ts2 * 32 + hf * 16) ^ ((lq & 7) << 4);
                int vo1 = ((1 * 32 + lq) * 64 + ts2 * 32 + hf * 16) ^ ((lq & 7) << 4);
                s16x8 vf0 = *reinterpret_cast<const s16x8*>(vb_ + vo0);
                s16x8 vf1 = *reinterpret_cast<const s16x8*>(vb_ + vo1);
                s16x8 pf = ts2 ? pf1.v : pf0.v;
                oacc0 = __builtin_amdgcn_mfma_f32_32x32x16_bf16(vf0, pf, oacc0, 0, 0, 0);
                oacc1 = __builtin_amdgcn_mfma_f32_32x32x16_bf16(vf1, pf, oacc1, 0, 0, 0);
            }
        }
        __syncthreads();  // everyone done reading buf[cur]
        if (j + 1 < nsteps) {
            *reinterpret_cast<uint4*>(reinterpret_cast<char*>(&kbuf[cur ^ 1][0]) + kwo) = ks;
            *reinterpret_cast<uint4*>(reinterpret_cast<char*>(&vbuf[cur ^ 1][0]) + vwo) = vs;
        }
    }

    if (l < 32) {
        pm[(size_t)slot * 128 + w * 32 + l] = m;
        pl[(size_t)slot * 128 + w * 32 + l] = ssum;
    }
    float* po = pO + (size_t)slot * 8192;  // [64 h][128 q]
#pragma unroll
    for (int g = 0; g < 16; ++g) {
        int hrow = (g & 3) + 8 * (g >> 2) + 4 * hf;
        po[hrow * 128 + w * 32 + lq] = oacc0[g];
        po[(32 + hrow) * 128 + w * 32 + lq] = oacc1[g];
    }
}

// ---- merge partials: one block per (b, 128-row qtile) ----
__global__ __launch_bounds__(256) void k_merge(const float* __restrict__ pm,
                                               const float* __restrict__ pl,
                                               const float* __restrict__ pO,
                                               float* __restrict__ out) {
    int qt = blockIdx.x & 31, b = blockIdx.x >> 5;
    int a = qt >> 2, r = qt & 3, nch = a + 1;
    int slot0 = b * SLOTS_PER_B + 2 * a * (a + 1) + r * (a + 1);

    __shared__ float wgt[8][128];
    __shared__ float invl[128];
    __shared__ float tr[64][130];

    int t = threadIdx.x;
    if (t < 128) {
        float M = -3e38f;
        for (int cc = 0; cc < nch; ++cc)
            M = fmaxf(M, pm[(size_t)(slot0 + cc) * 128 + t]);
        float L = 0.f;
        for (int cc = 0; cc < nch; ++cc) {
            float g = EXP2(pm[(size_t)(slot0 + cc) * 128 + t] - M);
            wgt[cc][t] = g;
            L += pl[(size_t)(slot0 + cc) * 128 + t] * g;
        }
        invl[t] = 1.0f / L;
    }
    __syncthreads();

    float4 acc[8] = {};
    for (int cc = 0; cc < nch; ++cc) {
        const float4* pp = reinterpret_cast<const float4*>(pO + (size_t)(slot0 + cc) * 8192);
#pragma unroll
        for (int it = 0; it < 8; ++it) {
            int idx = it * 256 + t, h = idx >> 5, qc = idx & 31;
            float4 vv = pp[h * 32 + qc];
            float4 w4 = *reinterpret_cast<const float4*>(&wgt[cc][qc * 4]);
            acc[it].x += vv.x * w4.x; acc[it].y += vv.y * w4.y;
            acc[it].z += vv.z * w4.z; acc[it].w += vv.w * w4.w;
        }
    }
#pragma unroll
    for (int it = 0; it < 8; ++it) {
        int idx = it * 256 + t, h = idx >> 5, qc = idx & 31;
        tr[h][qc * 4 + 0] = acc[it].x * invl[qc * 4 + 0];
        tr[h][qc * 4 + 1] = acc[it].y * invl[qc * 4 + 1];
        tr[h][qc * 4 + 2] = acc[it].z * invl[qc * 4 + 2];
        tr[h][qc * 4 + 3] = acc[it].w * invl[qc * 4 + 3];
    }
    __syncthreads();

    int q = t >> 1, half = t & 1;
    size_t obase = ((size_t)b * TT + qt * 128 + q) * 64 + half * 32;
#pragma unroll
    for (int jj = 0; jj < 8; ++jj) {
        float4 o;
        o.x = tr[half * 32 + jj * 4 + 0][q];
        o.y = tr[half * 32 + jj * 4 + 1][q];
        o.z = tr[half * 32 + jj * 4 + 2][q];
        o.w = tr[half * 32 + jj * 4 + 3][q];
        *reinterpret_cast<float4*>(out + obase + jj * 4) = o;
    }
}

extern "C" void kernel_launch(void* const* d_in, const int* in_sizes, int n_in,
                              void* d_out, int out_size, void* d_ws, size_t ws_size,
                              hipStream_t stream) {
    const float* q  = (const float*)d_in[0];
    const float* k  = (const float*)d_in[1];
    const float* v  = (const float*)d_in[2];
    const float* wq = (const float*)d_in[3];
    const float* wk = (const float*)d_in[4];
    const float* wv = (const float*)d_in[5];
    float* out = (float*)d_out;

    char* ws = (char*)d_ws;
    ushort* qh = (ushort*)(ws);                   // 2 MB   [16384][64] bf16
    ushort* kh = (ushort*)(ws + (2ull << 20));    // 2 MB   [16384][64] bf16
    ushort* vt = (ushort*)(ws + (4ull << 20));    // 2 MB   [64][16384] bf16
    ushort* wt = (ushort*)(ws + (6ull << 20));    // 384 KB [3][64][1024] bf16
    float*  pm = (float*)(ws + (7ull << 20));     // 288 KB [576][128]
    float*  pl = (float*)(ws + (7ull << 20) + (512u << 10));  // 288 KB
    float*  pO = (float*)(ws + (8ull << 20));     // 18.9 MB [576][64][128]

    k_wtrans<<<768, 256, 0, stream>>>(wq, wk, wv, wt);
    k_proj<<<768, 256, 0, stream>>>(q, k, v, wt, qh, kh, vt);
    k_attn<<<dim3(8, 32, 4), 256, 0, stream>>>(qh, kh, vt, pm, pl, pO);
    k_merge<<<128, 256, 0, stream>>>(pm, pl, pO, out);
}